// Round 1
// baseline (344.581 us; speedup 1.0000x reference)
//
#include <hip/hip_runtime.h>
#include <stdint.h>

// Problem constants (from reference setup_inputs / module constants)
#define BATCH   8
#define NPTS    8192
#define SCH     1024
#define KNN     32
#define TOPC    5
#define MAXIT   16

// ---------------------------------------------------------------------------
// Exact-rounding helpers: reference (numpy/jax CPU) computes squares and sums
// with separate mul/add roundings — forbid FMA contraction via *_rn intrinsics.
// ---------------------------------------------------------------------------
__device__ __forceinline__ float d2_norn(float ax, float ay, float az,
                                         float bx, float by, float bz) {
    float dx = __fsub_rn(ax, bx);
    float dy = __fsub_rn(ay, by);
    float dz = __fsub_rn(az, bz);
    return __fadd_rn(__fadd_rn(__fmul_rn(dx, dx), __fmul_rn(dy, dy)),
                     __fmul_rn(dz, dz));
}

__device__ __forceinline__ uint64_t wave_min_u64(uint64_t k) {
#pragma unroll
    for (int off = 32; off > 0; off >>= 1) {
        uint64_t o = (uint64_t)__shfl_xor((unsigned long long)k, off, 64);
        k = (o < k) ? o : k;
    }
    return k;
}

__device__ __forceinline__ void insert4(uint64_t key, uint64_t& k0, uint64_t& k1,
                                        uint64_t& k2, uint64_t& k3) {
    if (key < k3) {
        k3 = key;
        if (k3 < k2) { uint64_t t = k2; k2 = k3; k3 = t; }
        if (k2 < k1) { uint64_t t = k1; k1 = k2; k2 = t; }
        if (k1 < k0) { uint64_t t = k0; k0 = k1; k1 = t; }
    }
}

// ---------------------------------------------------------------------------
// Kernel A: one wave per chain (b,s). Runs the full refine loop to convergence.
// Writes unsorted results + conv iteration into workspace.
// ---------------------------------------------------------------------------
__global__ __launch_bounds__(256) void refine_kernel(
    const float* __restrict__ xyz, const float* __restrict__ center,
    const int* __restrict__ idx_in,
    float* __restrict__ pts_ws, int* __restrict__ idx_ws,
    int* __restrict__ grp_ws, int* __restrict__ conv_ws) {
    const int wave = (int)((blockIdx.x * blockDim.x + threadIdx.x) >> 6);
    const int lane = (int)(threadIdx.x & 63);
    if (wave >= BATCH * SCH) return;
    const int b = wave >> 10;      // / SCH
    const int s = wave & 1023;     // % SCH
    const float* __restrict__ pc = xyz + (size_t)b * NPTS * 3;

    // current query point and its label
    const size_t ch = (size_t)b * SCH + s;
    float qx = center[ch * 3 + 0];
    float qy = center[ch * 3 + 1];
    float qz = center[ch * 3 + 2];
    int qidx = idx_in[ch];

    int conv = MAXIT;
    int my_ind = 0;  // lane j (<32) holds ind[j] after extraction

    for (int it = 0;; ++it) {
        // ---- brute-force KNN scan: per-lane top-4 over 128 strided points ---
        uint64_t k0 = ~0ull, k1 = ~0ull, k2 = ~0ull, k3 = ~0ull;
        uint64_t em0 = 0ull, em1 = 0ull;  // extracted-point bitmask (this lane)
        int cnt = 4;
#pragma unroll 4
        for (int t = 0; t < NPTS / 64; ++t) {
            const int p = lane + (t << 6);
            const float* pp = pc + p * 3;
            const float d2 = d2_norn(qx, qy, qz, pp[0], pp[1], pp[2]);
            const uint64_t key = ((uint64_t)__float_as_uint(d2) << 13) | (uint32_t)p;
            insert4(key, k0, k1, k2, k3);
        }

        // ---- 32 extraction rounds: global min of lane heads (keys unique) ---
        for (int r = 0; r < KNN; ++r) {
            const uint64_t gmin = wave_min_u64(k0);
            const int widx = (int)(gmin & 0x1FFFull);
            if (lane == r) my_ind = widx;
            if (k0 == gmin) {  // exactly one winner lane (keys unique)
                const int t = widx >> 6;
                if (t < 64) em0 |= (1ull << t);
                else        em1 |= (1ull << (t - 64));
                k0 = k1; k1 = k2; k2 = k3; k3 = ~0ull;
                if (--cnt == 0) {  // rare refill: rescan non-extracted points
                    k0 = k1 = k2 = k3 = ~0ull;
                    for (int t2 = 0; t2 < NPTS / 64; ++t2) {
                        const bool ex = (t2 < 64) ? ((em0 >> t2) & 1ull)
                                                  : ((em1 >> (t2 - 64)) & 1ull);
                        if (ex) continue;
                        const int p = lane + (t2 << 6);
                        const float* pp = pc + p * 3;
                        const float d2 = d2_norn(qx, qy, qz, pp[0], pp[1], pp[2]);
                        const uint64_t key =
                            ((uint64_t)__float_as_uint(d2) << 13) | (uint32_t)p;
                        insert4(key, k0, k1, k2, k3);
                    }
                    cnt = 4;
                }
            }
        }

        if (it == MAXIT) { conv = MAXIT; break; }

        // ---- centroid of the 32 neighbors (sequential sum, matches ref) ----
        float nx = 0.f, ny = 0.f, nz = 0.f;
        if (lane < KNN) {
            const float* pp = pc + my_ind * 3;
            nx = pp[0]; ny = pp[1]; nz = pp[2];
        }
        float sx = 0.f, sy = 0.f, sz = 0.f;
#pragma unroll
        for (int j = 0; j < KNN; ++j) {
            sx = __fadd_rn(sx, __shfl(nx, j, 64));
            sy = __fadd_rn(sy, __shfl(ny, j, 64));
            sz = __fadd_rn(sz, __shfl(nz, j, 64));
        }
        const float gx = __fmul_rn(sx, 0.03125f);
        const float gy = __fmul_rn(sy, 0.03125f);
        const float gz = __fmul_rn(sz, 0.03125f);

        // ---- distance of each neighbor to centroid (sqrt for tie fidelity) -
        float dj;
        {
            const float dx = __fsub_rn(nx, gx);
            const float dy = __fsub_rn(ny, gy);
            const float dz = __fsub_rn(nz, gz);
            dj = sqrtf(__fadd_rn(__fadd_rn(__fmul_rn(dx, dx), __fmul_rn(dy, dy)),
                                 __fmul_rn(dz, dz)));
        }
        if (lane >= KNN) dj = __builtin_inff();
        const float d0 = __shfl(dj, 0, 64);

        // in_top: element 0 wins ties, so rank0 = #{j: dj < d0}; in_top <=> rank0 <= 4
        const unsigned long long bal = __ballot(dj < d0);
        const bool in_top = (__popcll(bal) <= TOPC - 1);
        if (in_top) { conv = it; break; }

        // move target: lexicographic argmin of (dist_j, j)
        const uint64_t ak = ((uint64_t)__float_as_uint(dj) << 6) | (uint32_t)lane;
        const uint64_t amin = wave_min_u64(ak);
        const int jmin = (int)(amin & 63ull);
        const int new_idx = __shfl(my_ind, jmin, 64);
        qidx = new_idx;
        const float* np_ = pc + new_idx * 3;
        qx = np_[0]; qy = np_[1]; qz = np_[2];
    }

    // ---- record result -----------------------------------------------------
    if (lane < KNN) grp_ws[ch * KNN + lane] = my_ind;
    if (lane == 0) {
        pts_ws[ch * 3 + 0] = qx;
        pts_ws[ch * 3 + 1] = qy;
        pts_ws[ch * 3 + 2] = qz;
        idx_ws[ch] = qidx;
        conv_ws[ch] = conv;
    }
}

// ---------------------------------------------------------------------------
// Kernel B: per batch, stable rank by (conv, s) and scatter to final layout.
// Outputs written as float values (indices are < 2^24, exact in fp32).
// ---------------------------------------------------------------------------
__global__ __launch_bounds__(1024) void order_kernel(
    const float* __restrict__ pts_ws, const int* __restrict__ idx_ws,
    const int* __restrict__ grp_ws, const int* __restrict__ conv_ws,
    float* __restrict__ out) {
    const int b = (int)blockIdx.x;
    const int s = (int)threadIdx.x;
    __shared__ int convs[SCH];
    const size_t ch = (size_t)b * SCH + s;
    const int myc = conv_ws[ch];
    convs[s] = myc;
    __syncthreads();

    int pos = 0;
    for (int t = 0; t < SCH; ++t) {
        const int c = convs[t];
        pos += (c < myc) || (c == myc && t < s);
    }

    float* __restrict__ C  = out;                                  // (B,S,3)
    float* __restrict__ I1 = out + (size_t)BATCH * SCH * 3;        // (B,S)
    float* __restrict__ I2 = I1 + (size_t)BATCH * SCH;             // (B,S,K)
    const size_t o = (size_t)b * SCH + pos;
    C[o * 3 + 0] = pts_ws[ch * 3 + 0];
    C[o * 3 + 1] = pts_ws[ch * 3 + 1];
    C[o * 3 + 2] = pts_ws[ch * 3 + 2];
    I1[o] = (float)idx_ws[ch];
#pragma unroll
    for (int k = 0; k < KNN; ++k) I2[o * KNN + k] = (float)grp_ws[ch * KNN + k];
}

extern "C" void kernel_launch(void* const* d_in, const int* in_sizes, int n_in,
                              void* d_out, int out_size, void* d_ws, size_t ws_size,
                              hipStream_t stream) {
    const float* xyz    = (const float*)d_in[0];  // (8,8192,3) f32
    const float* center = (const float*)d_in[1];  // (8,1024,3) f32
    const int*   idx_in = (const int*)d_in[2];    // (8,1024)   i32
    float* out = (float*)d_out;

    // workspace layout (~1.16 MB total)
    char* w = (char*)d_ws;
    float* pts_ws  = (float*)w;                                       // 8192*3 f32
    int*   idx_ws  = (int*)(w + (size_t)BATCH * SCH * 3 * 4);         // 8192 i32
    int*   grp_ws  = (int*)((char*)idx_ws + (size_t)BATCH * SCH * 4); // 8192*32 i32
    int*   conv_ws = (int*)((char*)grp_ws + (size_t)BATCH * SCH * KNN * 4);

    const int chains = BATCH * SCH;           // 8192 waves, 1 wave per chain
    const int threads = 256;                  // 4 chains per block
    const int blocks = chains * 64 / threads; // 2048
    refine_kernel<<<blocks, threads, 0, stream>>>(xyz, center, idx_in,
                                                  pts_ws, idx_ws, grp_ws, conv_ws);
    order_kernel<<<BATCH, SCH, 0, stream>>>(pts_ws, idx_ws, grp_ws, conv_ws, out);
}

// Round 2
// 342.877 us; speedup vs baseline: 1.0050x; 1.0050x over previous
//
#include <hip/hip_runtime.h>
#include <stdint.h>

#define BATCH   8
#define NPTS    8192
#define SCH     1024
#define KNN     32
#define TOPC    5
#define MAXIT   16

typedef unsigned long long ull;
typedef float vf2 __attribute__((ext_vector_type(2)));
typedef float vf4 __attribute__((ext_vector_type(4)));

// sentinel: unpacks to +inf d2, never enters top-32 (each lane sees 128 >= 4 real)
#define SENTKEY ((((ull)0x7F800000u) << 13) | 0x1FFFull)

// ---------------------------------------------------------------------------
// Exact d2: separate mul/add roundings (no FMA contraction), order ((dx2+dy2)+dz2)
// matches numpy. Vector form may select v_pk_mul/add_f32 (same per-lane rounding).
// ---------------------------------------------------------------------------
__device__ __forceinline__ float d2_exact(vf4 q, vf4 p) {
#pragma clang fp contract(off)
    vf2 d = q.xy - p.xy;
    vf2 s = d * d;
    float dz = q.z - p.z;
    float sz = dz * dz;
    return (s.x + s.y) + sz;
}

__device__ __forceinline__ void insert_top4(ull key, ull& k0, ull& k1, ull& k2,
                                            ull& k3, float& th) {
    if (key < k3) {
        k3 = key;
        { bool c = k3 < k2; ull mn = c ? k3 : k2, mx = c ? k2 : k3; k2 = mn; k3 = mx; }
        { bool c = k2 < k1; ull mn = c ? k2 : k1, mx = c ? k1 : k2; k1 = mn; k2 = mx; }
        { bool c = k1 < k0; ull mn = c ? k1 : k0, mx = c ? k0 : k1; k0 = mn; k1 = mx; }
        th = __uint_as_float((uint32_t)(k3 >> 13));
    }
}

// scan 128 strided points per lane, keep sorted top-4 (unique 45-bit keys)
__device__ __forceinline__ void scan_top4(const vf4* __restrict__ P, vf4 q, int lane,
                                          ull& k0, ull& k1, ull& k2, ull& k3) {
    k0 = k1 = k2 = k3 = SENTKEY;
    float th = __builtin_inff();
    const vf4* __restrict__ L = P + lane;
    vf4 b0 = L[0], b1 = L[64], b2 = L[128], b3 = L[192];
#pragma unroll 4
    for (int t = 0; t < 128; t += 4) {
        vf4 n0 = b0, n1 = b1, n2 = b2, n3 = b3;
        if (t + 4 < 128) {
            const vf4* __restrict__ Q = L + (size_t)(t + 4) * 64;
            n0 = Q[0]; n1 = Q[64]; n2 = Q[128]; n3 = Q[192];
        }
        {
            float d2 = d2_exact(q, b0);
            if (d2 <= th)
                insert_top4(((ull)__float_as_uint(d2) << 13) | (uint32_t)(lane + t * 64),
                            k0, k1, k2, k3, th);
        }
        {
            float d2 = d2_exact(q, b1);
            if (d2 <= th)
                insert_top4(((ull)__float_as_uint(d2) << 13) | (uint32_t)(lane + (t + 1) * 64),
                            k0, k1, k2, k3, th);
        }
        {
            float d2 = d2_exact(q, b2);
            if (d2 <= th)
                insert_top4(((ull)__float_as_uint(d2) << 13) | (uint32_t)(lane + (t + 2) * 64),
                            k0, k1, k2, k3, th);
        }
        {
            float d2 = d2_exact(q, b3);
            if (d2 <= th)
                insert_top4(((ull)__float_as_uint(d2) << 13) | (uint32_t)(lane + (t + 3) * 64),
                            k0, k1, k2, k3, th);
        }
        b0 = n0; b1 = n1; b2 = n2; b3 = n3;
    }
}

// bitonic helpers
__device__ __forceinline__ ull cx(ull v, int xl, bool keepmin) {
    ull o = (ull)__shfl_xor((unsigned long long)v, xl, 64);
    return ((v < o) == keepmin) ? v : o;
}
__device__ __forceinline__ void cswap(ull& a, ull& b, bool up) {
    bool lt = a < b;
    ull mn = lt ? a : b, mx = lt ? b : a;
    a = up ? mn : mx;
    b = up ? mx : mn;
}

// ---------------------------------------------------------------------------
// Rare fallback: round-1 serial extraction with refill (exact, slow, ~8%/KNN).
// ---------------------------------------------------------------------------
__device__ __attribute__((noinline)) int serial_topk(const vf4* __restrict__ P, vf4 q,
                                                     int lane) {
    ull k0 = SENTKEY, k1 = SENTKEY, k2 = SENTKEY, k3 = SENTKEY;
    float th = __builtin_inff();
    for (int t = 0; t < 128; ++t) {
        int p = lane + t * 64;
        float d2 = d2_exact(q, P[p]);
        if (d2 <= th)
            insert_top4(((ull)__float_as_uint(d2) << 13) | (uint32_t)p, k0, k1, k2, k3, th);
    }
    ull em0 = 0ull, em1 = 0ull;
    int cnt = 4;
    int my_ind = 0;
    for (int r = 0; r < KNN; ++r) {
        ull gmin = k0;
#pragma unroll
        for (int off = 32; off; off >>= 1) {
            ull o = (ull)__shfl_xor((unsigned long long)gmin, off, 64);
            gmin = o < gmin ? o : gmin;
        }
        int widx = (int)(gmin & 0x1FFFull);
        if (lane == r) my_ind = widx;
        if (k0 == gmin) {
            int tt = widx >> 6;
            if (tt < 64) em0 |= 1ull << tt;
            else         em1 |= 1ull << (tt - 64);
            k0 = k1; k1 = k2; k2 = k3; k3 = SENTKEY;
            if (--cnt == 0) {
                k0 = k1 = k2 = k3 = SENTKEY;
                float th2 = __builtin_inff();
                for (int t2 = 0; t2 < 128; ++t2) {
                    bool ex = (t2 < 64) ? ((em0 >> t2) & 1ull) : ((em1 >> (t2 - 64)) & 1ull);
                    if (ex) continue;
                    int p = lane + t2 * 64;
                    float d2 = d2_exact(q, P[p]);
                    if (d2 <= th2)
                        insert_top4(((ull)__float_as_uint(d2) << 13) | (uint32_t)p,
                                    k0, k1, k2, k3, th2);
                }
                cnt = 4;
            }
        }
    }
    return my_ind;
}

// ---------------------------------------------------------------------------
// Prep: xyz (B,N,3) -> padded float4 SoA for 1-load coalesced scans
// ---------------------------------------------------------------------------
__global__ __launch_bounds__(256) void prep_kernel(const float* __restrict__ xyz,
                                                   vf4* __restrict__ pc4) {
    int i = (int)(blockIdx.x * blockDim.x + threadIdx.x);
    if (i < BATCH * NPTS) {
        vf4 v;
        v.x = xyz[(size_t)i * 3 + 0];
        v.y = xyz[(size_t)i * 3 + 1];
        v.z = xyz[(size_t)i * 3 + 2];
        v.w = 0.f;
        pc4[i] = v;
    }
}

// ---------------------------------------------------------------------------
// Main refine: one wave per chain
// ---------------------------------------------------------------------------
__global__ __launch_bounds__(256) void refine_kernel(
    const vf4* __restrict__ pc4, const float* __restrict__ center,
    const int* __restrict__ idx_in,
    float* __restrict__ pts_ws, int* __restrict__ idx_ws,
    int* __restrict__ grp_ws, int* __restrict__ conv_ws) {
    const int wv = (int)((blockIdx.x * blockDim.x + threadIdx.x) >> 6);
    const int lane = (int)(threadIdx.x & 63);
    const int w = (int)(threadIdx.x >> 6);
    if (wv >= BATCH * SCH) return;
    const int b = wv >> 10;
    const vf4* __restrict__ P = pc4 + (size_t)b * NPTS;

    __shared__ vf4 nbh[4][KNN];

    const size_t ch = (size_t)wv;
    vf4 q;
    q.x = center[ch * 3 + 0];
    q.y = center[ch * 3 + 1];
    q.z = center[ch * 3 + 2];
    q.w = 0.f;
    int qidx = idx_in[ch];

    int conv = MAXIT;
    int my_ind = 0;

    for (int it = 0;; ++it) {
        // ---- KNN: per-lane top-4 then wave bitonic sort of 256 candidates ----
        ull k0, k1, k2, k3;
        scan_top4(P, q, lane, k0, k1, k2, k3);
        const ull prek3 = k3;

        const bool odd = (lane & 1) != 0;
        ull a0 = odd ? k3 : k0;
        ull a1 = odd ? k2 : k1;
        ull a2 = odd ? k1 : k2;
        ull a3 = odd ? k0 : k3;
#pragma unroll
        for (int kk = 8; kk <= 256; kk <<= 1) {
            const bool up = (lane & (kk >> 2)) == 0;
#pragma unroll
            for (int d = kk >> 1; d >= 4; d >>= 1) {
                const int xl = d >> 2;
                const bool keepmin = (up == ((lane & xl) == 0));
                a0 = cx(a0, xl, keepmin);
                a1 = cx(a1, xl, keepmin);
                a2 = cx(a2, xl, keepmin);
                a3 = cx(a3, xl, keepmin);
            }
            cswap(a0, a2, up); cswap(a1, a3, up);
            cswap(a0, a1, up); cswap(a2, a3, up);
        }
        // rank r lives at lane r>>2, reg r&3; tau = rank-31 key
        const ull tau = (ull)__shfl((unsigned long long)a3, 7, 64);
        const ull bad = __ballot(prek3 < tau);
        if (bad != 0ull) {
            my_ind = serial_topk(P, q, lane);   // lane may have truncated a winner
        } else {
            const int src = lane >> 2;
            const uint32_t lo0 = (uint32_t)__shfl((int)(uint32_t)a0, src, 64);
            const uint32_t lo1 = (uint32_t)__shfl((int)(uint32_t)a1, src, 64);
            const uint32_t lo2 = (uint32_t)__shfl((int)(uint32_t)a2, src, 64);
            const uint32_t lo3 = (uint32_t)__shfl((int)(uint32_t)a3, src, 64);
            const int sel = lane & 3;
            uint32_t lo = (sel == 0) ? lo0 : (sel == 1) ? lo1 : (sel == 2) ? lo2 : lo3;
            my_ind = (int)(lo & 0x1FFFu);
        }

        if (it == MAXIT) break;   // conv stays MAXIT ("active" path)

        // ---- centroid: stage 32 neighbor points to LDS, sequential fold ----
        vf4 myp = q;
        if (lane < KNN) {
            myp = P[my_ind];
            nbh[w][lane] = myp;
        }
        __asm__ volatile("s_waitcnt lgkmcnt(0)" ::: "memory");
        float sx = 0.f, sy = 0.f, sz = 0.f;
#pragma unroll
        for (int j = 0; j < KNN; ++j) {
            vf4 pj = nbh[w][j];
            sx = __fadd_rn(sx, pj.x);
            sy = __fadd_rn(sy, pj.y);
            sz = __fadd_rn(sz, pj.z);
        }
        const float gx = __fmul_rn(sx, 0.03125f);
        const float gy = __fmul_rn(sy, 0.03125f);
        const float gz = __fmul_rn(sz, 0.03125f);

        // ---- per-neighbor distance to centroid (post-sqrt ordering) ----
        float dj = __builtin_inff();
        if (lane < KNN) {
            const float dx = __fsub_rn(myp.x, gx);
            const float dy = __fsub_rn(myp.y, gy);
            const float dz = __fsub_rn(myp.z, gz);
            dj = sqrtf(__fadd_rn(__fadd_rn(__fmul_rn(dx, dx), __fmul_rn(dy, dy)),
                                 __fmul_rn(dz, dz)));
        }
        const uint32_t db = __float_as_uint(dj);   // nonneg floats: bit order == fp order
        const uint32_t d0 = (uint32_t)__shfl((int)db, 0, 64);
        const ull bal = __ballot(db < d0);
        if (__popcll(bal) <= TOPC - 1) { conv = it; break; }

        // move target: lexicographic argmin of (dist, j) via 32-bit butterfly
        uint32_t m = db;
#pragma unroll
        for (int off = 32; off; off >>= 1) {
            uint32_t o = (uint32_t)__shfl_xor((int)m, off, 64);
            m = o < m ? o : m;
        }
        const ull balm = __ballot(db == m);
        const int jm = __ffsll((unsigned long long)balm) - 1;
        const int nidx = __shfl(my_ind, jm, 64);
        qidx = nidx;
        q = P[nidx];
        q.w = 0.f;
    }

    if (lane < KNN) grp_ws[ch * KNN + lane] = my_ind;
    if (lane == 0) {
        pts_ws[ch * 3 + 0] = q.x;
        pts_ws[ch * 3 + 1] = q.y;
        pts_ws[ch * 3 + 2] = q.z;
        idx_ws[ch] = qidx;
        conv_ws[ch] = conv;
    }
}

// ---------------------------------------------------------------------------
// Order: stable rank by (conv, s) via 17-bin counting; O(17) per thread
// ---------------------------------------------------------------------------
__global__ __launch_bounds__(1024) void order_kernel(
    const float* __restrict__ pts_ws, const int* __restrict__ idx_ws,
    const int* __restrict__ grp_ws, const int* __restrict__ conv_ws,
    float* __restrict__ out) {
    const int b = (int)blockIdx.x;
    const int s = (int)threadIdx.x;
    const int w = s >> 6, l = s & 63;
    __shared__ int wavecnt[16][MAXIT + 1];
    __shared__ int binbase[MAXIT + 1];
    const size_t ch = (size_t)b * SCH + s;
    const int c = conv_ws[ch];
    int rw = 0;
#pragma unroll
    for (int v = 0; v <= MAXIT; ++v) {
        ull bal = __ballot(c == v);
        if (l == 0) wavecnt[w][v] = (int)__popcll(bal);
        if (c == v) rw = (int)__popcll(bal & ((1ull << l) - 1ull));
    }
    __syncthreads();
    if (s == 0) {
        int acc = 0;
        for (int v = 0; v <= MAXIT; ++v) {
            int t = 0;
            for (int w2 = 0; w2 < 16; ++w2) t += wavecnt[w2][v];
            binbase[v] = acc;
            acc += t;
        }
    }
    __syncthreads();
    int pos = binbase[c] + rw;
    for (int w2 = 0; w2 < w; ++w2) pos += wavecnt[w2][c];

    float* __restrict__ C  = out;                              // (B,S,3)
    float* __restrict__ I1 = out + (size_t)BATCH * SCH * 3;    // (B,S)
    float* __restrict__ I2 = I1 + (size_t)BATCH * SCH;         // (B,S,K)
    const size_t o = (size_t)b * SCH + pos;
    C[o * 3 + 0] = pts_ws[ch * 3 + 0];
    C[o * 3 + 1] = pts_ws[ch * 3 + 1];
    C[o * 3 + 2] = pts_ws[ch * 3 + 2];
    I1[o] = (float)idx_ws[ch];
#pragma unroll
    for (int k = 0; k < KNN; ++k) I2[o * KNN + k] = (float)grp_ws[ch * KNN + k];
}

extern "C" void kernel_launch(void* const* d_in, const int* in_sizes, int n_in,
                              void* d_out, int out_size, void* d_ws, size_t ws_size,
                              hipStream_t stream) {
    const float* xyz    = (const float*)d_in[0];  // (8,8192,3) f32
    const float* center = (const float*)d_in[1];  // (8,1024,3) f32
    const int*   idx_in = (const int*)d_in[2];    // (8,1024)   i32
    float* out = (float*)d_out;

    // workspace layout (~2.3 MB)
    char* wp = (char*)d_ws;
    vf4* pc4 = (vf4*)wp;                                   // 65536 * 16B
    wp += (size_t)BATCH * NPTS * sizeof(vf4);
    float* pts_ws = (float*)wp;  wp += (size_t)BATCH * SCH * 3 * 4;
    int*   idx_ws = (int*)wp;    wp += (size_t)BATCH * SCH * 4;
    int*   grp_ws = (int*)wp;    wp += (size_t)BATCH * SCH * KNN * 4;
    int*   conv_ws = (int*)wp;

    prep_kernel<<<(BATCH * NPTS + 255) / 256, 256, 0, stream>>>(xyz, pc4);

    const int chains = BATCH * SCH;                 // 8192 waves, 1 per chain
    const int threads = 256;                        // 4 chains per block
    const int blocks = chains * 64 / threads;       // 2048
    refine_kernel<<<blocks, threads, 0, stream>>>(pc4, center, idx_in,
                                                  pts_ws, idx_ws, grp_ws, conv_ws);
    order_kernel<<<BATCH, SCH, 0, stream>>>(pts_ws, idx_ws, grp_ws, conv_ws, out);
}